// Round 5
// baseline (297.478 us; speedup 1.0000x reference)
//
#include <hip/hip_runtime.h>

#define B_ 4
#define S_ 2048
#define D_ 768
#define H_ 12
#define HD_ 64
#define T_ (B_ * S_)  // 8192

typedef __bf16 bf16x8 __attribute__((ext_vector_type(8)));
typedef __bf16 bf16x4 __attribute__((ext_vector_type(4)));
typedef float  f32x4  __attribute__((ext_vector_type(4)));

__device__ __forceinline__ f32x4 mfma16(bf16x8 a, bf16x8 b, f32x4 c) {
  return __builtin_amdgcn_mfma_f32_16x16x32_bf16(a, b, c, 0, 0, 0);
}

// async global->LDS, 16B per lane. LDS dest is wave-uniform base + lane*16.
__device__ __forceinline__ void gload16(const __bf16* g, __bf16* lds) {
  __builtin_amdgcn_global_load_lds(
      (__attribute__((address_space(1))) void*)g,
      (__attribute__((address_space(3))) void*)lds, 16, 0, 0);
}

// ---------------- fp32 -> bf16 convert (vectorized, optional scale) ----------
__global__ void cvt_f32_bf16(const float* __restrict__ in, __bf16* __restrict__ out,
                             int n4, float scale) {
  int i = blockIdx.x * blockDim.x + threadIdx.x;
  if (i >= n4) return;
  float4 v = reinterpret_cast<const float4*>(in)[i];
  bf16x4 o;
  o[0] = (__bf16)(v.x * scale);
  o[1] = (__bf16)(v.y * scale);
  o[2] = (__bf16)(v.z * scale);
  o[3] = (__bf16)(v.w * scale);
  reinterpret_cast<bf16x4*>(out)[i] = o;
}

// ---------------- GEMM: C[m][n] = sum_k A[m][k] * W[n][k]  (B^T layout) ------
template <int MODE>
__global__ __launch_bounds__(256, 2)
void gemm_bt(const __bf16* __restrict__ A,
             const __bf16* __restrict__ W0, const __bf16* __restrict__ W1,
             const __bf16* __restrict__ W2,
             __bf16* __restrict__ Oq, __bf16* __restrict__ Ok,
             __bf16* __restrict__ Ov,
             float* __restrict__ fout, const float* __restrict__ bias) {
  constexpr int K = D_;  // 768
  __shared__ __align__(16) __bf16 sA[128 * 32];
  __shared__ __align__(16) __bf16 sB[128 * 32];

  const int tid = threadIdx.x;
  const int l = tid & 63;
  const int w = tid >> 6;
  const int m0 = blockIdx.x * 128;

  int mat, n0;
  const __bf16* Wm;
  if (MODE == 0) {
    mat = blockIdx.y / 6;
    n0 = (blockIdx.y % 6) * 128;
    Wm = (mat == 0) ? W0 : (mat == 1) ? W1 : W2;
  } else {
    mat = 0;
    n0 = blockIdx.y * 128;
    Wm = W0;
  }

  const int srow = l >> 2;
  const int sk = (l & 3) * 8;
  const int c0 = w * 2, c1 = w * 2 + 1;
  const __bf16* gA0 = A + (m0 + c0 * 16 + srow) * K + sk;
  const __bf16* gA1 = A + (m0 + c1 * 16 + srow) * K + sk;
  const __bf16* gB0 = Wm + (n0 + c0 * 16 + srow) * K + sk;
  const __bf16* gB1 = Wm + (n0 + c1 * 16 + srow) * K + sk;
  __bf16* lA0 = &sA[c0 * 512];
  __bf16* lA1 = &sA[c1 * 512];
  __bf16* lB0 = &sB[c0 * 512];
  __bf16* lB1 = &sB[c1 * 512];

  f32x4 acc[4][4] = {};
  const int wr = w >> 1, wc = w & 1;
  const int fr = l & 15, fq = l >> 4;

  for (int kt = 0; kt < K / 32; ++kt) {
    const int ko = kt * 32;
    gload16(gA0 + ko, lA0);
    gload16(gA1 + ko, lA1);
    gload16(gB0 + ko, lB0);
    gload16(gB1 + ko, lB1);
    __syncthreads();
    bf16x8 af[4], bfr[4];
#pragma unroll
    for (int mi = 0; mi < 4; ++mi)
      af[mi] = *reinterpret_cast<const bf16x8*>(
          &sA[(wr * 64 + mi * 16 + fr) * 32 + fq * 8]);
#pragma unroll
    for (int ni = 0; ni < 4; ++ni)
      bfr[ni] = *reinterpret_cast<const bf16x8*>(
          &sB[(wc * 64 + ni * 16 + fr) * 32 + fq * 8]);
#pragma unroll
    for (int mi = 0; mi < 4; ++mi)
#pragma unroll
      for (int ni = 0; ni < 4; ++ni)
        acc[mi][ni] = mfma16(af[mi], bfr[ni], acc[mi][ni]);
    __syncthreads();
  }

#pragma unroll
  for (int mi = 0; mi < 4; ++mi) {
    const int mbase = m0 + wr * 64 + mi * 16 + fq * 4;
#pragma unroll
    for (int ni = 0; ni < 4; ++ni) {
      const int o = n0 + wc * 64 + ni * 16 + fr;
#pragma unroll
      for (int r = 0; r < 4; ++r) {
        const float v = acc[mi][ni][r];
        const int mm = mbase + r;
        if (MODE == 1) {
          fout[mm * D_ + o] = v + bias[o];
        } else {
          const int b = mm >> 11, s = mm & (S_ - 1);
          const int h = o >> 6, hd = o & 63;
          if (mat == 0)
            Oq[((size_t)((b * H_ + h) * S_ + s)) * HD_ + hd] = (__bf16)v;
          else if (mat == 1)
            Ok[((size_t)((b * H_ + h) * S_ + s)) * HD_ + hd] = (__bf16)v;
          else
            Ov[((size_t)((b * H_ + h) * HD_ + hd)) * S_ + s] = (__bf16)v;
        }
      }
    }
  }
}

// ---------------- causal flash attention, swapped-operand, lane-local softmax -
// grid = (S/16) * B * H 64-thread blocks, depth-sorted (deepest causal chains
// dispatch first). Per wave: 16 q-rows; KV tiles of 64.
// QK^T computed SWAPPED (mfma(K,Q) -> S^T): lane owns q = qb + (lane&15), its
// 16 scores per tile are in-register -> softmax is in-lane trees + 2 shfl_xor.
// PV also swapped (mfma(V^T,P) -> O^T): rescale + final 1/l are lane-local.
// P staged through a 2 KB XOR-swizzled LDS tile (write S^T, read A-layout).
__global__ __launch_bounds__(64, 6)
void attn_kernel(const __bf16* __restrict__ Q, const __bf16* __restrict__ Kt,
                 const __bf16* __restrict__ Vt, __bf16* __restrict__ C) {
  __shared__ __align__(16) __bf16 sP[16 * 64];  // 2 KB, swizzled
  const int l = threadIdx.x;
  const int fr = l & 15, fq = l >> 4;
  const int bx = blockIdx.x;
  const int tile = (S_ / 16 - 1) - bx / (B_ * H_);
  const int bh = bx % (B_ * H_);
  const int qb = tile * 16;

  const __bf16* qh = Q + (size_t)bh * S_ * HD_;
  const __bf16* kh = Kt + (size_t)bh * S_ * HD_;
  const __bf16* vh = Vt + (size_t)bh * HD_ * S_;
  char* sPb = reinterpret_cast<char*>(sP);

  // Q fragment (B-operand): col=q=fr, k = ks*32 + fq*8 ..
  bf16x8 qf[2];
#pragma unroll
  for (int ks = 0; ks < 2; ++ks)
    qf[ks] = *reinterpret_cast<const bf16x8*>(
        &qh[(size_t)(qb + fr) * HD_ + ks * 32 + fq * 8]);

  // acc = O^T fragments: acc[dt][r] = O[d = dt*16 + fq*4 + r][q = fr]
  f32x4 acc[4] = {};
  float mrow = -1e30f, lrow = 0.f;
  const int qi = qb + fr;  // this lane's q row

  const int ntiles = (qb + 16 + 63) >> 6;  // ceil((qb+16)/64)
  for (int t = 0; t < ntiles; ++t) {
    const int kv0 = t << 6;

    // QK^T swapped: s[c][r] = S[kv = kv0 + c*16 + fq*4 + r][q = qb + fr]
    f32x4 s[4];
    __builtin_amdgcn_s_setprio(1);
#pragma unroll
    for (int c = 0; c < 4; ++c) {
      bf16x8 kf0 = *reinterpret_cast<const bf16x8*>(
          &kh[(size_t)(kv0 + c * 16 + fr) * HD_ + fq * 8]);
      bf16x8 kf1 = *reinterpret_cast<const bf16x8*>(
          &kh[(size_t)(kv0 + c * 16 + fr) * HD_ + 32 + fq * 8]);
      f32x4 z = {};
      z = mfma16(kf0, qf[0], z);
      z = mfma16(kf1, qf[1], z);
      s[c] = z;
    }
    __builtin_amdgcn_s_setprio(0);

    // issue V loads now: latency hides under softmax + P staging
    bf16x8 vf[4][2];
#pragma unroll
    for (int dt = 0; dt < 4; ++dt) {
      vf[dt][0] = *reinterpret_cast<const bf16x8*>(
          &vh[(size_t)(dt * 16 + fr) * S_ + kv0 + fq * 8]);
      vf[dt][1] = *reinterpret_cast<const bf16x8*>(
          &vh[(size_t)(dt * 16 + fr) * S_ + kv0 + 32 + fq * 8]);
    }

    if (kv0 + 63 > qb) {  // tile may contain masked elements (min q-row = qb)
#pragma unroll
      for (int c = 0; c < 4; ++c)
#pragma unroll
        for (int r = 0; r < 4; ++r) {
          const int kvi = kv0 + c * 16 + fq * 4 + r;
          if (kvi > qi) s[c][r] = -1e30f;
        }
    }

    // lane-local softmax over this lane's 16 scores + 2 cross-lane combines
    float tm = -1e30f;
#pragma unroll
    for (int c = 0; c < 4; ++c)
#pragma unroll
      for (int r = 0; r < 4; ++r) tm = fmaxf(tm, s[c][r]);
    tm = fmaxf(tm, __shfl_xor(tm, 16));
    tm = fmaxf(tm, __shfl_xor(tm, 32));
    const float mn = fmaxf(mrow, tm);
    const float fac = __expf(mrow - mn);
    mrow = mn;
    float sum = 0.f;
#pragma unroll
    for (int c = 0; c < 4; ++c)
#pragma unroll
      for (int r = 0; r < 4; ++r) {
        const float p = __expf(s[c][r] - mn);
        s[c][r] = p;
        sum += p;
      }
    sum += __shfl_xor(sum, 16);
    sum += __shfl_xor(sum, 32);
    lrow = lrow * fac + sum;
#pragma unroll
    for (int dt = 0; dt < 4; ++dt)
#pragma unroll
      for (int r = 0; r < 4; ++r) acc[dt][r] *= fac;  // fac is lane-local

    // stage P^T -> LDS as P[q][kv], row = q = fr, XOR-swizzle (fr&7)<<4.
    // lane's 4 values for c are kv = c*16 + fq*4 + (0..3): one 8 B store.
#pragma unroll
    for (int c = 0; c < 4; ++c) {
      bf16x4 pc;
#pragma unroll
      for (int r = 0; r < 4; ++r) pc[r] = (__bf16)s[c][r];
      const int bo = ((c * 32 + fq * 8)) ^ ((fr & 7) << 4);
      *reinterpret_cast<bf16x4*>(sPb + fr * 128 + bo) = pc;
    }
    // read P as A/B fragment: row = q = fr, k(kv) = ks*32 + fq*8 ..
    bf16x8 pa[2];
#pragma unroll
    for (int ks = 0; ks < 2; ++ks) {
      const int bo = (ks * 64 + fq * 16) ^ ((fr & 7) << 4);
      pa[ks] = *reinterpret_cast<const bf16x8*>(sPb + fr * 128 + bo);
    }

    // PV swapped: O^T[d][q] += V^T[d][kv] * P[kv->k][q]
    __builtin_amdgcn_s_setprio(1);
#pragma unroll
    for (int dt = 0; dt < 4; ++dt) {
      acc[dt] = mfma16(vf[dt][0], pa[0], acc[dt]);
      acc[dt] = mfma16(vf[dt][1], pa[1], acc[dt]);
    }
    __builtin_amdgcn_s_setprio(0);
  }

  // epilogue: all lane-local. acc[dt][r] -> C[q = qb+fr][d = dt*16+fq*4+r]
  const int b = bh / H_, h = bh % H_;
  const float inv_l = 1.0f / lrow;
#pragma unroll
  for (int dt = 0; dt < 4; ++dt) {
    bf16x4 ov;
#pragma unroll
    for (int r = 0; r < 4; ++r) ov[r] = (__bf16)(acc[dt][r] * inv_l);
    *reinterpret_cast<bf16x4*>(
        &C[((size_t)(b * S_ + qb + fr)) * D_ + h * HD_ + dt * 16 + fq * 4]) =
        ov;
  }
}

// ---------------- workspace layout (bf16 elements) ---------------------------
static constexpr size_t XB_OFF = 0;
static constexpr size_t WQ_OFF = XB_OFF + (size_t)T_ * D_;
static constexpr size_t WK_OFF = WQ_OFF + (size_t)D_ * D_;
static constexpr size_t WV_OFF = WK_OFF + (size_t)D_ * D_;
static constexpr size_t WO_OFF = WV_OFF + (size_t)D_ * D_;
static constexpr size_t Q_OFF = WO_OFF + (size_t)D_ * D_;
static constexpr size_t K_OFF = Q_OFF + (size_t)T_ * D_;
static constexpr size_t V_OFF = K_OFF + (size_t)T_ * D_;
static constexpr size_t C_OFF = V_OFF + (size_t)T_ * D_;

extern "C" void kernel_launch(void* const* d_in, const int* in_sizes, int n_in,
                              void* d_out, int out_size, void* d_ws,
                              size_t ws_size, hipStream_t stream) {
  const float* x = (const float*)d_in[0];
  const float* wq = (const float*)d_in[1];
  const float* wk = (const float*)d_in[2];
  const float* wv = (const float*)d_in[3];
  const float* wo = (const float*)d_in[4];
  const float* bo = (const float*)d_in[5];
  float* out = (float*)d_out;
  __bf16* ws = (__bf16*)d_ws;

  __bf16* xb = ws + XB_OFF;
  __bf16* wqb = ws + WQ_OFF;
  __bf16* wkb = ws + WK_OFF;
  __bf16* wvb = ws + WV_OFF;
  __bf16* wob = ws + WO_OFF;
  __bf16* qbuf = ws + Q_OFF;
  __bf16* kbuf = ws + K_OFF;
  __bf16* vbuf = ws + V_OFF;
  __bf16* cbuf = ws + C_OFF;

  {
    int n4 = T_ * D_ / 4;
    cvt_f32_bf16<<<(n4 + 255) / 256, 256, 0, stream>>>(x, xb, n4, 1.0f);
    n4 = D_ * D_ / 4;
    cvt_f32_bf16<<<(n4 + 255) / 256, 256, 0, stream>>>(wq, wqb, n4, 1.0f);
    // fold 1/sqrt(64) into K (exact in bf16: power of two)
    cvt_f32_bf16<<<(n4 + 255) / 256, 256, 0, stream>>>(wk, wkb, n4, 0.125f);
    cvt_f32_bf16<<<(n4 + 255) / 256, 256, 0, stream>>>(wv, wvb, n4, 1.0f);
    cvt_f32_bf16<<<(n4 + 255) / 256, 256, 0, stream>>>(wo, wob, n4, 1.0f);
  }

  gemm_bt<0><<<dim3(T_ / 128, 18), 256, 0, stream>>>(
      xb, wqb, wkb, wvb, qbuf, kbuf, vbuf, nullptr, nullptr);

  attn_kernel<<<dim3((S_ / 16) * B_ * H_), 64, 0, stream>>>(qbuf, kbuf, vbuf,
                                                            cbuf);

  gemm_bt<1><<<dim3(T_ / 128, 6), 256, 0, stream>>>(
      cbuf, wob, nullptr, nullptr, nullptr, nullptr, nullptr, out, bo);
}

// Round 6
// 217.849 us; speedup vs baseline: 1.3655x; 1.3655x over previous
//
#include <hip/hip_runtime.h>

#define B_ 4
#define S_ 2048
#define D_ 768
#define H_ 12
#define HD_ 64
#define T_ (B_ * S_)  // 8192

typedef __bf16 bf16x8 __attribute__((ext_vector_type(8)));
typedef __bf16 bf16x4 __attribute__((ext_vector_type(4)));
typedef float  f32x4  __attribute__((ext_vector_type(4)));

__device__ __forceinline__ f32x4 mfma16(bf16x8 a, bf16x8 b, f32x4 c) {
  return __builtin_amdgcn_mfma_f32_16x16x32_bf16(a, b, c, 0, 0, 0);
}

// async global->LDS, 16B per lane. LDS dest is wave-uniform base + lane*16.
__device__ __forceinline__ void gload16(const __bf16* g, __bf16* lds) {
  __builtin_amdgcn_global_load_lds(
      (__attribute__((address_space(1))) void*)g,
      (__attribute__((address_space(3))) void*)lds, 16, 0, 0);
}

// ---------------- fp32 -> bf16 convert (vectorized, optional scale) ----------
__global__ void cvt_f32_bf16(const float* __restrict__ in, __bf16* __restrict__ out,
                             int n4, float scale) {
  int i = blockIdx.x * blockDim.x + threadIdx.x;
  if (i >= n4) return;
  float4 v = reinterpret_cast<const float4*>(in)[i];
  bf16x4 o;
  o[0] = (__bf16)(v.x * scale);
  o[1] = (__bf16)(v.y * scale);
  o[2] = (__bf16)(v.z * scale);
  o[3] = (__bf16)(v.w * scale);
  reinterpret_cast<bf16x4*>(out)[i] = o;
}

// ---------------- GEMM: C[m][n] = sum_k A[m][k] * W[n][k]  (B^T layout) ------
template <int MODE>
__global__ __launch_bounds__(256, 2)
void gemm_bt(const __bf16* __restrict__ A,
             const __bf16* __restrict__ W0, const __bf16* __restrict__ W1,
             const __bf16* __restrict__ W2,
             __bf16* __restrict__ Oq, __bf16* __restrict__ Ok,
             __bf16* __restrict__ Ov,
             float* __restrict__ fout, const float* __restrict__ bias) {
  constexpr int K = D_;  // 768
  __shared__ __align__(16) __bf16 sA[128 * 32];
  __shared__ __align__(16) __bf16 sB[128 * 32];

  const int tid = threadIdx.x;
  const int l = tid & 63;
  const int w = tid >> 6;
  const int m0 = blockIdx.x * 128;

  int mat, n0;
  const __bf16* Wm;
  if (MODE == 0) {
    mat = blockIdx.y / 6;
    n0 = (blockIdx.y % 6) * 128;
    Wm = (mat == 0) ? W0 : (mat == 1) ? W1 : W2;
  } else {
    mat = 0;
    n0 = blockIdx.y * 128;
    Wm = W0;
  }

  const int srow = l >> 2;
  const int sk = (l & 3) * 8;
  const int c0 = w * 2, c1 = w * 2 + 1;
  const __bf16* gA0 = A + (m0 + c0 * 16 + srow) * K + sk;
  const __bf16* gA1 = A + (m0 + c1 * 16 + srow) * K + sk;
  const __bf16* gB0 = Wm + (n0 + c0 * 16 + srow) * K + sk;
  const __bf16* gB1 = Wm + (n0 + c1 * 16 + srow) * K + sk;
  __bf16* lA0 = &sA[c0 * 512];
  __bf16* lA1 = &sA[c1 * 512];
  __bf16* lB0 = &sB[c0 * 512];
  __bf16* lB1 = &sB[c1 * 512];

  f32x4 acc[4][4] = {};
  const int wr = w >> 1, wc = w & 1;
  const int fr = l & 15, fq = l >> 4;

  for (int kt = 0; kt < K / 32; ++kt) {
    const int ko = kt * 32;
    gload16(gA0 + ko, lA0);
    gload16(gA1 + ko, lA1);
    gload16(gB0 + ko, lB0);
    gload16(gB1 + ko, lB1);
    __syncthreads();
    bf16x8 af[4], bfr[4];
#pragma unroll
    for (int mi = 0; mi < 4; ++mi)
      af[mi] = *reinterpret_cast<const bf16x8*>(
          &sA[(wr * 64 + mi * 16 + fr) * 32 + fq * 8]);
#pragma unroll
    for (int ni = 0; ni < 4; ++ni)
      bfr[ni] = *reinterpret_cast<const bf16x8*>(
          &sB[(wc * 64 + ni * 16 + fr) * 32 + fq * 8]);
#pragma unroll
    for (int mi = 0; mi < 4; ++mi)
#pragma unroll
      for (int ni = 0; ni < 4; ++ni)
        acc[mi][ni] = mfma16(af[mi], bfr[ni], acc[mi][ni]);
    __syncthreads();
  }

#pragma unroll
  for (int mi = 0; mi < 4; ++mi) {
    const int mbase = m0 + wr * 64 + mi * 16 + fq * 4;
#pragma unroll
    for (int ni = 0; ni < 4; ++ni) {
      const int o = n0 + wc * 64 + ni * 16 + fr;
#pragma unroll
      for (int r = 0; r < 4; ++r) {
        const float v = acc[mi][ni][r];
        const int mm = mbase + r;
        if (MODE == 1) {
          fout[mm * D_ + o] = v + bias[o];
        } else {
          const int b = mm >> 11, s = mm & (S_ - 1);
          const int h = o >> 6, hd = o & 63;
          if (mat == 0)
            Oq[((size_t)((b * H_ + h) * S_ + s)) * HD_ + hd] = (__bf16)v;
          else if (mat == 1)
            Ok[((size_t)((b * H_ + h) * S_ + s)) * HD_ + hd] = (__bf16)v;
          else
            Ov[((size_t)((b * H_ + h) * HD_ + hd)) * S_ + s] = (__bf16)v;
        }
      }
    }
  }
}

// ---------------- causal flash attention, swapped-operand, QBLK=32 ------------
// grid = 3072 one-wave blocks. Block mapping: xcd = bx&7, j = bx>>3;
// head = xcd + 8*(j%6)  -> each XCD sees only 6 heads (3 MB K/V fits its L2);
// tile = 63 - j/6       -> deepest causal chains dispatch first.
// Wave owns 32 q-rows as two swapped-layout q-groups sharing all K/V loads.
// QK^T swapped (mfma(K,Q) -> S^T): lane owns q = qb + g*16 + (lane&15);
// softmax is in-lane trees + 2 shfl_xor. PV swapped (mfma(V^T,P) -> O^T).
__global__ __launch_bounds__(64, 4)
void attn_kernel(const __bf16* __restrict__ Q, const __bf16* __restrict__ Kt,
                 const __bf16* __restrict__ Vt, __bf16* __restrict__ C) {
  __shared__ __align__(16) __bf16 sP[32 * 64];  // 4 KB, swizzled
  const int l = threadIdx.x;
  const int fr = l & 15, fq = l >> 4;
  const int bx = blockIdx.x;
  const int xcd = bx & 7;
  const int j = bx >> 3;             // [0, 384)
  const int bh = xcd + 8 * (j % 6);  // head in [0, 48)
  const int tile = 63 - j / 6;       // [0, 64), deep first
  const int qb = tile * 32;

  const __bf16* qh = Q + (size_t)bh * S_ * HD_;
  const __bf16* kh = Kt + (size_t)bh * S_ * HD_;
  const __bf16* vh = Vt + (size_t)bh * HD_ * S_;
  char* sPb = reinterpret_cast<char*>(sP);

  // Q fragments (B-operand): group g covers q = qb + g*16 + fr
  bf16x8 qf[2][2];
#pragma unroll
  for (int g = 0; g < 2; ++g)
#pragma unroll
    for (int ks = 0; ks < 2; ++ks)
      qf[g][ks] = *reinterpret_cast<const bf16x8*>(
          &qh[(size_t)(qb + g * 16 + fr) * HD_ + ks * 32 + fq * 8]);

  // acc[g][dt][r] = O^T[d = dt*16 + fq*4 + r][q = qb + g*16 + fr]
  f32x4 acc[2][4] = {};
  float mrow[2] = {-1e30f, -1e30f}, lrow[2] = {0.f, 0.f};

  const int ntiles = (qb + 32 + 63) >> 6;  // ceil((qb+32)/64)
  for (int t = 0; t < ntiles; ++t) {
    const int kv0 = t << 6;

    // QK^T swapped, K loads shared by both q-groups:
    // s[g][c][r] = S[kv = kv0 + c*16 + fq*4 + r][q = qb + g*16 + fr]
    f32x4 s[2][4];
    __builtin_amdgcn_s_setprio(1);
#pragma unroll
    for (int c = 0; c < 4; ++c) {
      bf16x8 kf0 = *reinterpret_cast<const bf16x8*>(
          &kh[(size_t)(kv0 + c * 16 + fr) * HD_ + fq * 8]);
      bf16x8 kf1 = *reinterpret_cast<const bf16x8*>(
          &kh[(size_t)(kv0 + c * 16 + fr) * HD_ + 32 + fq * 8]);
#pragma unroll
      for (int g = 0; g < 2; ++g) {
        f32x4 z = {};
        z = mfma16(kf0, qf[g][0], z);
        z = mfma16(kf1, qf[g][1], z);
        s[g][c] = z;
      }
    }
    __builtin_amdgcn_s_setprio(0);

    if (kv0 + 63 > qb) {  // tile may contain masked elements (min q-row = qb)
#pragma unroll
      for (int g = 0; g < 2; ++g) {
        const int qi = qb + g * 16 + fr;
#pragma unroll
        for (int c = 0; c < 4; ++c)
#pragma unroll
          for (int r = 0; r < 4; ++r) {
            const int kvi = kv0 + c * 16 + fq * 4 + r;
            if (kvi > qi) s[g][c][r] = -1e30f;
          }
      }
    }

    // lane-local softmax per q-group (16 in-register scores + 2 shfl_xor)
#pragma unroll
    for (int g = 0; g < 2; ++g) {
      float tm = -1e30f;
#pragma unroll
      for (int c = 0; c < 4; ++c)
#pragma unroll
        for (int r = 0; r < 4; ++r) tm = fmaxf(tm, s[g][c][r]);
      tm = fmaxf(tm, __shfl_xor(tm, 16));
      tm = fmaxf(tm, __shfl_xor(tm, 32));
      const float mn = fmaxf(mrow[g], tm);
      const float fac = __expf(mrow[g] - mn);
      mrow[g] = mn;
      float sum = 0.f;
#pragma unroll
      for (int c = 0; c < 4; ++c)
#pragma unroll
        for (int r = 0; r < 4; ++r) {
          const float p = __expf(s[g][c][r] - mn);
          s[g][c][r] = p;
          sum += p;
        }
      sum += __shfl_xor(sum, 16);
      sum += __shfl_xor(sum, 32);
      lrow[g] = lrow[g] * fac + sum;
#pragma unroll
      for (int dt = 0; dt < 4; ++dt)
#pragma unroll
        for (int r = 0; r < 4; ++r) acc[g][dt][r] *= fac;  // lane-local fac
    }

    // stage P -> LDS as P[q][kv], row = g*16 + fr, XOR-swizzle (fr&7)<<4
#pragma unroll
    for (int g = 0; g < 2; ++g)
#pragma unroll
      for (int c = 0; c < 4; ++c) {
        bf16x4 pc;
#pragma unroll
        for (int r = 0; r < 4; ++r) pc[r] = (__bf16)s[g][c][r];
        const int bo = (c * 32 + fq * 8) ^ ((fr & 7) << 4);
        *reinterpret_cast<bf16x4*>(sPb + (g * 16 + fr) * 128 + bo) = pc;
      }
    // read P as A-fragment: row = q, k(kv) = ks*32 + fq*8 ..
    bf16x8 pa[2][2];
#pragma unroll
    for (int g = 0; g < 2; ++g)
#pragma unroll
      for (int ks = 0; ks < 2; ++ks) {
        const int bo = (ks * 64 + fq * 16) ^ ((fr & 7) << 4);
        pa[g][ks] =
            *reinterpret_cast<const bf16x8*>(sPb + (g * 16 + fr) * 128 + bo);
      }

    // PV swapped: O^T[d][q] += V^T[d][kv] * P[kv][q]; prefetch V by one dt
    bf16x8 vc0 = *reinterpret_cast<const bf16x8*>(
        &vh[(size_t)(0 * 16 + fr) * S_ + kv0 + fq * 8]);
    bf16x8 vc1 = *reinterpret_cast<const bf16x8*>(
        &vh[(size_t)(0 * 16 + fr) * S_ + kv0 + 32 + fq * 8]);
#pragma unroll
    for (int dt = 0; dt < 4; ++dt) {
      bf16x8 vn0, vn1;
      if (dt < 3) {
        vn0 = *reinterpret_cast<const bf16x8*>(
            &vh[(size_t)((dt + 1) * 16 + fr) * S_ + kv0 + fq * 8]);
        vn1 = *reinterpret_cast<const bf16x8*>(
            &vh[(size_t)((dt + 1) * 16 + fr) * S_ + kv0 + 32 + fq * 8]);
      }
      __builtin_amdgcn_s_setprio(1);
#pragma unroll
      for (int g = 0; g < 2; ++g) {
        acc[g][dt] = mfma16(vc0, pa[g][0], acc[g][dt]);
        acc[g][dt] = mfma16(vc1, pa[g][1], acc[g][dt]);
      }
      __builtin_amdgcn_s_setprio(0);
      vc0 = vn0;
      vc1 = vn1;
    }
  }

  // epilogue: all lane-local. acc[g][dt][r] -> C[q][d = dt*16 + fq*4 + r]
  const int b = bh / H_, h = bh % H_;
#pragma unroll
  for (int g = 0; g < 2; ++g) {
    const float inv_l = 1.0f / lrow[g];
    const int qrow = qb + g * 16 + fr;
#pragma unroll
    for (int dt = 0; dt < 4; ++dt) {
      bf16x4 ov;
#pragma unroll
      for (int r = 0; r < 4; ++r) ov[r] = (__bf16)(acc[g][dt][r] * inv_l);
      *reinterpret_cast<bf16x4*>(
          &C[((size_t)(b * S_ + qrow)) * D_ + h * HD_ + dt * 16 + fq * 4]) =
          ov;
    }
  }
}

// ---------------- workspace layout (bf16 elements) ---------------------------
static constexpr size_t XB_OFF = 0;
static constexpr size_t WQ_OFF = XB_OFF + (size_t)T_ * D_;
static constexpr size_t WK_OFF = WQ_OFF + (size_t)D_ * D_;
static constexpr size_t WV_OFF = WK_OFF + (size_t)D_ * D_;
static constexpr size_t WO_OFF = WV_OFF + (size_t)D_ * D_;
static constexpr size_t Q_OFF = WO_OFF + (size_t)D_ * D_;
static constexpr size_t K_OFF = Q_OFF + (size_t)T_ * D_;
static constexpr size_t V_OFF = K_OFF + (size_t)T_ * D_;
static constexpr size_t C_OFF = V_OFF + (size_t)T_ * D_;

extern "C" void kernel_launch(void* const* d_in, const int* in_sizes, int n_in,
                              void* d_out, int out_size, void* d_ws,
                              size_t ws_size, hipStream_t stream) {
  const float* x = (const float*)d_in[0];
  const float* wq = (const float*)d_in[1];
  const float* wk = (const float*)d_in[2];
  const float* wv = (const float*)d_in[3];
  const float* wo = (const float*)d_in[4];
  const float* bo = (const float*)d_in[5];
  float* out = (float*)d_out;
  __bf16* ws = (__bf16*)d_ws;

  __bf16* xb = ws + XB_OFF;
  __bf16* wqb = ws + WQ_OFF;
  __bf16* wkb = ws + WK_OFF;
  __bf16* wvb = ws + WV_OFF;
  __bf16* wob = ws + WO_OFF;
  __bf16* qbuf = ws + Q_OFF;
  __bf16* kbuf = ws + K_OFF;
  __bf16* vbuf = ws + V_OFF;
  __bf16* cbuf = ws + C_OFF;

  {
    int n4 = T_ * D_ / 4;
    cvt_f32_bf16<<<(n4 + 255) / 256, 256, 0, stream>>>(x, xb, n4, 1.0f);
    n4 = D_ * D_ / 4;
    cvt_f32_bf16<<<(n4 + 255) / 256, 256, 0, stream>>>(wq, wqb, n4, 1.0f);
    // fold 1/sqrt(64) into K (exact in bf16: power of two)
    cvt_f32_bf16<<<(n4 + 255) / 256, 256, 0, stream>>>(wk, wkb, n4, 0.125f);
    cvt_f32_bf16<<<(n4 + 255) / 256, 256, 0, stream>>>(wv, wvb, n4, 1.0f);
    cvt_f32_bf16<<<(n4 + 255) / 256, 256, 0, stream>>>(wo, wob, n4, 1.0f);
  }

  gemm_bt<0><<<dim3(T_ / 128, 18), 256, 0, stream>>>(
      xb, wqb, wkb, wvb, qbuf, kbuf, vbuf, nullptr, nullptr);

  attn_kernel<<<dim3(3072), 64, 0, stream>>>(qbuf, kbuf, vbuf, cbuf);

  gemm_bt<1><<<dim3(T_ / 128, 6), 256, 0, stream>>>(
      cbuf, wob, nullptr, nullptr, nullptr, nullptr, nullptr, out, bo);
}